// Round 8
// baseline (277.722 us; speedup 1.0000x reference)
//
#include <hip/hip_runtime.h>
#include <hip/hip_bf16.h>

typedef __attribute__((ext_vector_type(8))) short bf16x8;
typedef __attribute__((ext_vector_type(4))) float f32x4;
typedef __attribute__((ext_vector_type(8))) unsigned short u16x8;

__device__ __forceinline__ unsigned short f2bf(float f) {
  union { float f; unsigned u; } c; c.f = f;
  unsigned u = c.u;
  u = (u + 0x7FFFu + ((u >> 16) & 1u)) >> 16;   // RNE
  return (unsigned short)u;
}

__device__ __forceinline__ void gld_lds16(const void* g, void* l) {
  __builtin_amdgcn_global_load_lds(
      (__attribute__((address_space(1))) unsigned int*)g,
      (__attribute__((address_space(3))) unsigned int*)l,
      16, 0, 0);
}

// lgkmcnt(0) (ds_reads already consumed by MFMA -> ~free) + raw barrier.
// Guarantees all waves' LDS reads completed before any post-barrier
// overwrite is issued, WITHOUT draining vmcnt (staging stays in flight).
#define BARD()                                          \
  do {                                                  \
    asm volatile("s_waitcnt lgkmcnt(0)" ::: "memory");  \
    asm volatile("s_barrier" ::: "memory");             \
  } while (0)

// ---------------- single fused conversion kernel (unchanged) ----------------
__global__ void cvt_all(const float* __restrict__ x, unsigned short* __restrict__ x16,
                        const float* __restrict__ Kw, unsigned short* __restrict__ K16,
                        const float* __restrict__ V, unsigned short* __restrict__ Vt,
                        float* __restrict__ lsum) {
  const int b = blockIdx.x;
  const int tid = threadIdx.x;
  if (b < 32) lsum[b * 256 + tid] = 0.f;

  if (b < 6144) {
    const float* in;
    unsigned short* out;
    int i;
    if (b < 4096) {
      in = x; out = x16; i = (b * 256 + tid) * 8;
    } else {
      in = Kw; out = K16; i = ((b - 4096) * 256 + tid) * 8;
    }
    const float4* p = (const float4*)(in + i);
    float4 a = p[0], bb = p[1];
    u16x8 r;
    r[0] = f2bf(a.x); r[1] = f2bf(a.y); r[2] = f2bf(a.z); r[3] = f2bf(a.w);
    r[4] = f2bf(bb.x); r[5] = f2bf(bb.y); r[6] = f2bf(bb.z); r[7] = f2bf(bb.w);
    *(u16x8*)(out + i) = r;
  } else {
    __shared__ unsigned short t[64][65];
    const int tile = b - 6144;
    const int p0 = (tile & 63) * 64;
    const int e0 = (tile >> 6) * 64;
    const int tx = tid & 63;
    const int ty = tid >> 6;
#pragma unroll
    for (int i = 0; i < 16; ++i) {
      int p = ty + i * 4;
      t[p][tx] = f2bf(V[(size_t)(p0 + p) * 1024 + e0 + tx]);
    }
    __syncthreads();
    const int op = (tid & 7) * 8;
    const int oe = tid >> 3;
#pragma unroll
    for (int h = 0; h < 2; ++h) {
      int e = oe + h * 32;
      u16x8 r;
#pragma unroll
      for (int i = 0; i < 8; ++i) r[i] = t[op + i][e];
      *(u16x8*)(Vt + (size_t)(e0 + e) * 4096 + p0 + op) = r;
    }
  }
}

// ---- 128x128-tile NT GEMM: deep pipeline + 2 co-resident blocks/CU --------
// A [M x Kd], B [N x Kd] row-major bf16. S = A.B^T.
// 4 waves (2x2), per-wave 64x64 out. LDS 64KB (2 bufs x (A 16K + B 16K))
// -> 2 blocks/CU; cross-block TLP fills barrier skew + drain stalls (m114).
// EPI==0: Kd=1024, grid 2048 (64m x 32n). P = exp2(scale*S) -> Pout + lsum.
// EPI==1: Kd=4096, grid 512  (64m x 8n).  C = S / lin[row].
//
// Per K-tile (2 barriers total):
//   p0: read bF(8)+aF0(4) | stage A(g+1)->buf[g^1] | 16 MFMA | BARD
//   p1: read aF1(4)       | stage B(g+2)->buf[g&1] | 16 MFMA | vmcnt(4) BARD
// vmcnt FIFO at p1 end: [B(g+1):4, A(g+1):4, B(g+2):4] -> vmcnt(4) drains
// B(g+1),A(g+1) (buf[g^1] fully staged), leaves B(g+2) in flight.
// WAR: A(g+1) overwrite issued after tile g-1's reads (BARD at g-1 p1);
// B(g+2) overwrites buf[g&1].B whose bF reads completed before p0's BARD.
// Tail staging wraps modulo NT (dummy, in-bounds, never consumed).
template <int EPI>
__global__ __launch_bounds__(256, 2) void gemm_db(
    const unsigned short* __restrict__ A, const unsigned short* __restrict__ B,
    unsigned short* __restrict__ Pout, float* __restrict__ lsum,
    float* __restrict__ Cout, const float* __restrict__ lin, float scale) {
  constexpr int Kd = EPI ? 4096 : 1024;
  constexpr int Nc = EPI ? 1024 : 4096;
  constexpr int NT = Kd / 64;             // 16 / 64 K-tiles (pow2)

  __shared__ __align__(16) char lds[65536];   // 2 x (A 16K | B 16K)

  const int tid = threadIdx.x;
  const int lane = tid & 63;
  const int w = tid >> 6;        // 4 waves
  const int wm = w >> 1;
  const int wn = w & 1;
  const int q = lane >> 4;
  const int ml = lane & 15;

  const int bid = blockIdx.x;
  const int wg = (bid & 7) * (EPI ? 64 : 256) + (bid >> 3);   // grid%8==0
  const int m_t = EPI ? (wg >> 3) : (wg >> 5);
  const int n_t = EPI ? (wg & 7) : (wg & 31);
  const int row0 = m_t * 128;
  const int col0 = n_t * 128;

  // Staging: 16B chunk c = tid + j*256 -> row (tid>>3)+j*32, slot tid&7.
  // LDS slot s of row r holds global k-chunk s^(r&7); (r&7) is j-invariant.
  const int cr = tid >> 3;
  const int ss = (tid & 7) ^ (cr & 7);
  const unsigned short* pA = A + (size_t)(row0 + cr) * Kd + ss * 8;
  const unsigned short* pB = B + (size_t)(col0 + cr) * Kd + ss * 8;
  char* ldsw = lds + w * 1024;   // wave-uniform dest base (HW adds lane*16)

  // Fragments: row = (wm|wn)*64 + x*16 + ml (row&7 == ml&7), logical k-chunk
  // ks*4+q -> swizzled byte = ((q^(ml&7))*16) ^ (ks*64).
  const int cc0 = (q ^ (ml & 7)) * 16;
  const int aOff = (wm * 64 + ml) * 128 + cc0;            // + mi*2048
  const int bOff = 16384 + (wn * 64 + ml) * 128 + cc0;    // + ni*2048

  f32x4 acc[4][4] = {};

  auto stA = [&](int t, int buf) {
    const unsigned short* s = pA + t * 64;
    char* d = ldsw + buf * 32768;
#pragma unroll
    for (int j = 0; j < 4; ++j) gld_lds16(s + (size_t)j * 32 * Kd, d + j * 4096);
  };
  auto stB = [&](int t, int buf) {
    const unsigned short* s = pB + t * 64;
    char* d = ldsw + buf * 32768 + 16384;
#pragma unroll
    for (int j = 0; j < 4; ++j) gld_lds16(s + (size_t)j * 32 * Kd, d + j * 4096);
  };

  // Prologue: tile0 (A+B) + B(1); drain tile0, keep B(1) in flight.
  stA(0, 0); stB(0, 0);
  stB(1 & (NT - 1), 1);
  asm volatile("s_waitcnt vmcnt(4)" ::: "memory");
  __builtin_amdgcn_s_barrier();

#pragma unroll 2
  for (int g = 0; g < NT; ++g) {
    const char* base = lds + (g & 1) * 32768;
    const int tA = (g + 1) & (NT - 1);
    const int tB = (g + 2) & (NT - 1);

    // ---- p0: bF + aF(0,1) reads, stage A(g+1), MFMA mi=0,1 ----
    bf16x8 bF[4][2], a0[2][2];
#pragma unroll
    for (int ni = 0; ni < 4; ++ni)
#pragma unroll
      for (int ks = 0; ks < 2; ++ks)
        bF[ni][ks] = *(const bf16x8*)(base + ((bOff + ni * 2048) ^ (ks * 64)));
#pragma unroll
    for (int i = 0; i < 2; ++i)
#pragma unroll
      for (int ks = 0; ks < 2; ++ks)
        a0[i][ks] = *(const bf16x8*)(base + ((aOff + i * 2048) ^ (ks * 64)));

    stA(tA, (g + 1) & 1);

    __builtin_amdgcn_s_setprio(1);
#pragma unroll
    for (int ks = 0; ks < 2; ++ks)
#pragma unroll
      for (int i = 0; i < 2; ++i)
#pragma unroll
        for (int ni = 0; ni < 4; ++ni)
          acc[i][ni] = __builtin_amdgcn_mfma_f32_16x16x32_bf16(
              a0[i][ks], bF[ni][ks], acc[i][ni], 0, 0, 0);
    __builtin_amdgcn_s_setprio(0);
    BARD();

    // ---- p1: aF(2,3) reads, stage B(g+2), MFMA mi=2,3 ----
    bf16x8 a1[2][2];
#pragma unroll
    for (int i = 0; i < 2; ++i)
#pragma unroll
      for (int ks = 0; ks < 2; ++ks)
        a1[i][ks] = *(const bf16x8*)(base + ((aOff + (2 + i) * 2048) ^ (ks * 64)));

    stB(tB, g & 1);

    __builtin_amdgcn_s_setprio(1);
#pragma unroll
    for (int ks = 0; ks < 2; ++ks)
#pragma unroll
      for (int i = 0; i < 2; ++i)
#pragma unroll
        for (int ni = 0; ni < 4; ++ni)
          acc[2 + i][ni] = __builtin_amdgcn_mfma_f32_16x16x32_bf16(
              a1[i][ks], bF[ni][ks], acc[2 + i][ni], 0, 0, 0);
    __builtin_amdgcn_s_setprio(0);
    asm volatile("s_waitcnt vmcnt(4)" ::: "memory");   // buf[g^1] fully staged
    BARD();
  }

  if constexpr (EPI == 0) {
#pragma unroll
    for (int mi = 0; mi < 4; ++mi) {
#pragma unroll
      for (int j = 0; j < 4; ++j) {
        const int gr = row0 + wm * 64 + mi * 16 + q * 4 + j;
        float rsum = 0.f;
#pragma unroll
        for (int ni = 0; ni < 4; ++ni) {
          const int gc = col0 + wn * 64 + ni * 16 + ml;
          float pv = exp2f(acc[mi][ni][j] * scale);  // scale includes log2(e)
          rsum += pv;
          Pout[(size_t)gr * Nc + gc] = f2bf(pv);
        }
        rsum += __shfl_xor(rsum, 1);
        rsum += __shfl_xor(rsum, 2);
        rsum += __shfl_xor(rsum, 4);
        rsum += __shfl_xor(rsum, 8);
        if (ml == 0) atomicAdd(&lsum[gr], rsum);
      }
    }
  } else {
#pragma unroll
    for (int mi = 0; mi < 4; ++mi) {
#pragma unroll
      for (int j = 0; j < 4; ++j) {
        const int gr = row0 + wm * 64 + mi * 16 + q * 4 + j;
        const float rl = 1.0f / lin[gr];
#pragma unroll
        for (int ni = 0; ni < 4; ++ni) {
          const int gc = col0 + wn * 64 + ni * 16 + ml;
          Cout[(size_t)gr * Nc + gc] = acc[mi][ni][j] * rl;
        }
      }
    }
  }
}

extern "C" void kernel_launch(void* const* d_in, const int* in_sizes, int n_in,
                              void* d_out, int out_size, void* d_ws,
                              size_t ws_size, hipStream_t stream) {
  const float* x = (const float*)d_in[0];   // [8192,1024]
  const float* Kw = (const float*)d_in[1];  // [4096,1024]
  const float* Vw = (const float*)d_in[2];  // [4096,1024]
  float* out = (float*)d_out;               // [8192,1024]
  char* ws = (char*)d_ws;

  unsigned short* x16  = (unsigned short*)(ws);                   // 16 MB
  unsigned short* K16  = (unsigned short*)(ws + (16u << 20));     //  8 MB
  unsigned short* V16t = (unsigned short*)(ws + (24u << 20));     //  8 MB
  float*          lsum = (float*)(ws + (32u << 20));              // 32 KB
  unsigned short* P16  = (unsigned short*)(ws + (33u << 20));     // 64 MB

  cvt_all<<<7168, 256, 0, stream>>>(x, x16, Kw, K16, Vw, V16t, lsum);

  // GEMM1: P = exp(x16 . K16^T / 32), row sums -> lsum.
  gemm_db<0><<<2048, 256, 0, stream>>>(
      x16, K16, P16, lsum, nullptr, nullptr,
      0.03125f * 1.44269504088896340736f);
  // GEMM2: out = (P16 . V16t^T) / lsum[row]
  gemm_db<1><<<512, 256, 0, stream>>>(
      P16, V16t, nullptr, nullptr, out, lsum, 0.f);
}

// Round 9
// 260.042 us; speedup vs baseline: 1.0680x; 1.0680x over previous
//
#include <hip/hip_runtime.h>
#include <hip/hip_bf16.h>

typedef __attribute__((ext_vector_type(8))) short bf16x8;
typedef __attribute__((ext_vector_type(4))) float f32x4;
typedef __attribute__((ext_vector_type(8))) unsigned short u16x8;
typedef __attribute__((ext_vector_type(2))) unsigned short u16x2;

__device__ __forceinline__ unsigned short f2bf(float f) {
  union { float f; unsigned u; } c; c.f = f;
  unsigned u = c.u;
  u = (u + 0x7FFFu + ((u >> 16) & 1u)) >> 16;   // RNE
  return (unsigned short)u;
}

__device__ __forceinline__ void gld_lds16(const void* g, void* l) {
  __builtin_amdgcn_global_load_lds(
      (__attribute__((address_space(1))) unsigned int*)g,
      (__attribute__((address_space(3))) unsigned int*)l,
      16, 0, 0);
}

// Raw workgroup barrier that is also a compiler memory fence (but NOT a
// vmcnt/lgkmcnt drain): compiler keeps its own counted lgkm waits inside.
#define BAR() asm volatile("s_barrier" ::: "memory")

// ---------------- fused conversion kernel (V-path vectorized) --------------
// [0,4096): x->x16 ; [4096,6144): K->K16 ; [6144,7168): V -> Vt (transpose).
__global__ void cvt_all(const float* __restrict__ x, unsigned short* __restrict__ x16,
                        const float* __restrict__ Kw, unsigned short* __restrict__ K16,
                        const float* __restrict__ V, unsigned short* __restrict__ Vt) {
  const int b = blockIdx.x;
  const int tid = threadIdx.x;

  if (b < 6144) {
    const float* in;
    unsigned short* out;
    int i;
    if (b < 4096) {
      in = x; out = x16; i = (b * 256 + tid) * 8;
    } else {
      in = Kw; out = K16; i = ((b - 4096) * 256 + tid) * 8;
    }
    const float4* p = (const float4*)(in + i);
    float4 a = p[0], bb = p[1];
    u16x8 r;
    r[0] = f2bf(a.x); r[1] = f2bf(a.y); r[2] = f2bf(a.z); r[3] = f2bf(a.w);
    r[4] = f2bf(bb.x); r[5] = f2bf(bb.y); r[6] = f2bf(bb.z); r[7] = f2bf(bb.w);
    *(u16x8*)(out + i) = r;
  } else {
    // 64x64 tile transpose: float4 global reads (16B/lane, G13), u16x2 LDS
    // writes, u16x8 vector stores. t padded to 66 -> read conflicts <=4-way.
    __shared__ unsigned short t[64][66];
    const int tile = b - 6144;
    const int p0 = (tile & 63) * 64;
    const int e0 = (tile >> 6) * 64;
    const int cg = (tid & 15) * 4;     // 4-col group
    const int pr = tid >> 4;           // 0..15, +16*i
#pragma unroll
    for (int i = 0; i < 4; ++i) {
      int p = pr + i * 16;
      float4 v = *(const float4*)(V + (size_t)(p0 + p) * 1024 + e0 + cg);
      u16x2 lo, hi;
      lo[0] = f2bf(v.x); lo[1] = f2bf(v.y);
      hi[0] = f2bf(v.z); hi[1] = f2bf(v.w);
      *(u16x2*)&t[p][cg] = lo;
      *(u16x2*)&t[p][cg + 2] = hi;
    }
    __syncthreads();
    const int op = (tid & 7) * 8;
    const int oe = tid >> 3;           // 0..31
#pragma unroll
    for (int h = 0; h < 2; ++h) {
      int e = oe + h * 32;
      u16x8 r;
#pragma unroll
      for (int i = 0; i < 8; ++i) r[i] = t[op + i][e];
      *(u16x8*)(Vt + (size_t)(e0 + e) * 4096 + p0 + op) = r;
    }
  }
}

// ---- 8-phase NT GEMM (round-7 exact: de-pinned, counted vmcnt) ------------
// A [M x Kd], B [N x Kd] row-major bf16. S = A.B^T.
// EPI==0: BM=256,BN=256, grid 512. P = exp2(scale*S) -> Pout bf16 + row sums.
// EPI==1: BM=128,BN=256, grid 256. C = S / lin[row] -> Cout fp32.
template <int EPI>
__global__ __launch_bounds__(512, 2) void gemm8p(
    const unsigned short* __restrict__ A, const unsigned short* __restrict__ B,
    unsigned short* __restrict__ Pout, float* __restrict__ lsum,
    float* __restrict__ Cout, const float* __restrict__ lin, float scale) {
  constexpr int BM = EPI ? 128 : 256;
  constexpr int Kd = EPI ? 4096 : 1024;
  constexpr int Nc = EPI ? 1024 : 4096;
  constexpr int NT = Kd / 64;             // 16 / 64 K-tiles (pow2)
  constexpr int AU = BM / 128;            // A 16KB units per tile (2 / 1)
  constexpr int NU = AU + 2;              // + 2 B units
  constexpr int M_rep = BM / 32;          // 8 / 4
  constexpr int PH = M_rep / 2;           // 4 / 2 phases per tile

  __shared__ __align__(16) char lds[2 * NU * 16384];   // 128 / 96 KB

  const int tid = threadIdx.x;
  const int lane = tid & 63;
  const int w = tid >> 6;
  const int wm = w >> 2;
  const int wn = w & 3;
  const int q = lane >> 4;
  const int ml = lane & 15;

  const int bid = blockIdx.x;
  const int wg = (bid & 7) * (EPI ? 32 : 64) + (bid >> 3);
  const int m_t = EPI ? (wg >> 2) : (wg >> 4);
  const int n_t = EPI ? (wg & 3) : (wg & 15);
  const int row0 = m_t * BM;
  const int col0 = n_t * 256;

  const int cr = tid >> 3;
  const int ss = (tid & 7) ^ (cr & 7);
  char* ldsw = lds + w * 1024;

  const int ccB = (q ^ (ml & 7)) * 16;
  const int aOff = (EPI ? 0 : wm) * 16384 + ((EPI ? wm * 64 : 0) + ml) * 128 + ccB;
  const int bOff = (AU + (wn >> 1)) * 16384 + ((wn & 1) * 64 + ml) * 128 + ccB;

  f32x4 acc[M_rep][4] = {};

  auto stA = [&](int a, int t, int buf) {
    const unsigned short* s = A + (size_t)(row0 + a * 128 + cr) * Kd + t * 64 + ss * 8;
    char* d = ldsw + (buf * NU + a) * 16384;
    gld_lds16(s, d);
    gld_lds16(s + (size_t)64 * Kd, d + 8192);
  };
  auto stB = [&](int b, int t, int buf) {
    const unsigned short* s = B + (size_t)(col0 + b * 128 + cr) * Kd + t * 64 + ss * 8;
    char* d = ldsw + (buf * NU + AU + b) * 16384;
    gld_lds16(s, d);
    gld_lds16(s + (size_t)64 * Kd, d + 8192);
  };

  // Prologue: tile0 fully + B(1); drain tile0 (vmcnt leaves B(1) in flight).
#pragma unroll
  for (int a = 0; a < AU; ++a) stA(a, 0, 0);
  stB(0, 0, 0); stB(1, 0, 0);
  stB(0, 1, 1); stB(1, 1, 1);
  asm volatile("s_waitcnt vmcnt(4)" ::: "memory");
  BAR();

  for (int g = 0; g < NT; ++g) {
    const char* base = lds + (g & 1) * (NU * 16384);
    const int tA = (g + 1) & (NT - 1);
    const int bufA = (g + 1) & 1;
    const int tB = (g + 2) & (NT - 1);
    const int bufB = g & 1;

    bf16x8 bF[4][2];
#pragma unroll
    for (int ni = 0; ni < 4; ++ni)
#pragma unroll
      for (int ks = 0; ks < 2; ++ks)
        bF[ni][ks] = *(const bf16x8*)(base + (bOff ^ (ks * 64)) + ni * 2048);

#pragma unroll
    for (int p = 0; p < PH; ++p) {
      bf16x8 aF[2][2];
#pragma unroll
      for (int i = 0; i < 2; ++i)
#pragma unroll
        for (int ks = 0; ks < 2; ++ks)
          aF[i][ks] = *(const bf16x8*)(base + ((aOff ^ (ks * 64)) + (2 * p + i) * 2048));

      if constexpr (EPI == 0) {
        if (p == 0) stA(0, tA, bufA);
        else if (p == 1) stA(1, tA, bufA);
        else if (p == 2) stB(0, tB, bufB);
        else stB(1, tB, bufB);
      } else {
        if (p == 0) stA(0, tA, bufA);
        else { stB(0, tB, bufB); stB(1, tB, bufB); }
      }

      BAR();
      __builtin_amdgcn_s_setprio(1);
#pragma unroll
      for (int ks = 0; ks < 2; ++ks)
#pragma unroll
        for (int i = 0; i < 2; ++i)
#pragma unroll
          for (int ni = 0; ni < 4; ++ni)
            acc[2 * p + i][ni] = __builtin_amdgcn_mfma_f32_16x16x32_bf16(
                aF[i][ks], bF[ni][ks], acc[2 * p + i][ni], 0, 0, 0);
      __builtin_amdgcn_s_setprio(0);
      if (p == PH - 1) asm volatile("s_waitcnt vmcnt(4)" ::: "memory");
      BAR();
    }
  }

  if constexpr (EPI == 0) {
#pragma unroll
    for (int mi = 0; mi < M_rep; ++mi) {
#pragma unroll
      for (int j = 0; j < 4; ++j) {
        const int gr = row0 + wm * (BM / 2) + mi * 16 + q * 4 + j;
        float rsum = 0.f;
#pragma unroll
        for (int ni = 0; ni < 4; ++ni) {
          const int gc = col0 + wn * 64 + ni * 16 + ml;
          float pv = exp2f(acc[mi][ni][j] * scale);  // scale includes log2(e)
          rsum += pv;
          Pout[(size_t)gr * Nc + gc] = f2bf(pv);
        }
        rsum += __shfl_xor(rsum, 1);
        rsum += __shfl_xor(rsum, 2);
        rsum += __shfl_xor(rsum, 4);
        rsum += __shfl_xor(rsum, 8);
        if (ml == 0) atomicAdd(&lsum[gr], rsum);
      }
    }
  } else {
#pragma unroll
    for (int mi = 0; mi < M_rep; ++mi) {
#pragma unroll
      for (int j = 0; j < 4; ++j) {
        const int gr = row0 + wm * (BM / 2) + mi * 16 + q * 4 + j;
        const float rl = 1.0f / lin[gr];
#pragma unroll
        for (int ni = 0; ni < 4; ++ni) {
          const int gc = col0 + wn * 64 + ni * 16 + ml;
          Cout[(size_t)gr * Nc + gc] = acc[mi][ni][j] * rl;
        }
      }
    }
  }
}

extern "C" void kernel_launch(void* const* d_in, const int* in_sizes, int n_in,
                              void* d_out, int out_size, void* d_ws,
                              size_t ws_size, hipStream_t stream) {
  const float* x = (const float*)d_in[0];   // [8192,1024]
  const float* Kw = (const float*)d_in[1];  // [4096,1024]
  const float* Vw = (const float*)d_in[2];  // [4096,1024]
  float* out = (float*)d_out;               // [8192,1024]
  char* ws = (char*)d_ws;

  unsigned short* x16  = (unsigned short*)(ws);                   // 16 MB
  unsigned short* K16  = (unsigned short*)(ws + (16u << 20));     //  8 MB
  unsigned short* V16t = (unsigned short*)(ws + (24u << 20));     //  8 MB
  float*          lsum = (float*)(ws + (32u << 20));              // 32 KB
  unsigned short* P16  = (unsigned short*)(ws + (33u << 20));     // 64 MB

  hipMemsetAsync(lsum, 0, 8192 * sizeof(float), stream);
  cvt_all<<<7168, 256, 0, stream>>>(x, x16, Kw, K16, Vw, V16t);

  // GEMM1: P = exp(x16 . K16^T / 32), row sums -> lsum.
  gemm8p<0><<<512, 512, 0, stream>>>(
      x16, K16, P16, lsum, nullptr, nullptr,
      0.03125f * 1.44269504088896340736f);
  // GEMM2: out = (P16 . V16t^T) / lsum[row]
  gemm8p<1><<<256, 512, 0, stream>>>(
      P16, V16t, nullptr, nullptr, out, lsum, 0.f);
}